// Round 13
// baseline (492.420 us; speedup 1.0000x reference)
//
#include <hip/hip_runtime.h>
#include <cstddef>

#define T_STEPS  512
#define D_IN     5
#define NB       16      // batch elements per block
#define NTHREADS 1024    // 16 waves; each wave owns 1 L0 M-tile + 1 L1 M-tile
#define LOG2E    1.4426950408889634f

typedef _Float16 half8 __attribute__((ext_vector_type(8)));
typedef float    f32x4 __attribute__((ext_vector_type(4)));

// Builtin MFMA (R11/R12-proven): compiler manages accumulator hazards and
// interleaves epilogue VALU with MFMA issue (inline-asm pinned both; R12
// removing the s_nop fences was worth -60us).
#define MFMA(A, B, C) __builtin_amdgcn_mfma_f32_16x16x32_f16((A), (B), (C), 0, 0, 0)

// Weights pre-scaled by log2e (2*log2e for g rows) so activations use v_exp_f32.
// Single-rcp-per-product cell update: 7 trans ops (5 exp2 + 2 rcp) -- the
// mathematical floor for sigmoid x3 + tanh x2 with shared denominators.
__device__ __forceinline__ float lstm_cell(const f32x4 acc, float& c) {
    const float tg = __builtin_amdgcn_exp2f(acc[2]);
    const float ui = __builtin_amdgcn_exp2f(-acc[0]);
    const float uf = __builtin_amdgcn_exp2f(-acc[1]);
    const float A  = 1.0f + uf;
    const float Bd = (1.0f + ui) * (1.0f + tg);
    const float r  = __builtin_amdgcn_rcpf(A * Bd);
    c = fmaf(c, Bd, (tg - 1.0f) * A) * r;
    const float ca = fminf(c * (2.0f * LOG2E), 126.0f);
    const float tc = __builtin_amdgcn_exp2f(ca);
    const float uo = __builtin_amdgcn_exp2f(-acc[3]);
    return (tc - 1.0f) * __builtin_amdgcn_rcpf((1.0f + uo) * (1.0f + tc));
}

// h-plane swizzle: row = 64 halves = 8 x 16B blocks; block j of row n lives at
// j ^ (n & 7). b128 reads conflict-free; scalar 2B writes 2-way (free).
__device__ __forceinline__ int hswz8(int n, int u) {
    return (((u >> 3) ^ (n & 7)) << 3) | (u & 7);
}

__global__ __launch_bounds__(NTHREADS, 4)
void lstm_stack_mfma17(const float* __restrict__ x,
                       const float* __restrict__ W_ih0,
                       const float* __restrict__ W_hh0,
                       const float* __restrict__ b_ih0,
                       const float* __restrict__ b_hh0,
                       const float* __restrict__ W_ih1,
                       const float* __restrict__ W_hh1,
                       const float* __restrict__ b_ih1,
                       const float* __restrict__ b_hh1,
                       const float* __restrict__ W1,
                       const float* __restrict__ b1,
                       const float* __restrict__ W2,
                       const float* __restrict__ b2,
                       float* __restrict__ out)
{
    // Lag-2 layer pipeline: interval t computes h1(t) (L0) and h2(t-2) (L1).
    // h planes double-buffered (write p=t&1, read q=p^1).
    // x double-buffered: at interval t, READ x(t+1) from buf (t+1)&1=q and
    // WRITE x(t+2) to buf (t+2)&1=p -- one barrier between producer and
    // consumer, no race; with unroll-2 every buffer index constant-folds
    // (R12's triple buffer cost mod-3 bookkeeping every interval).
    __shared__ _Float16 h1b[2][NB][64];         // h1, swizzled
    __shared__ _Float16 h2b[2][NB][64];         // h2, swizzled
    // x row = 40 halves (20 dw): bank = (20*n16+4*quad)%32, 2-way only.
    // Slots 0..4 written; 5..39 stay zero (zeros feed quads 1-3 of the frag).
    __shared__ _Float16 x_pack[2][NB][40];
    __shared__ float h2f[NB][68];   // exact fp32 h2(T-1) for FC head
    __shared__ float zb[NB][36];    // FC-head z buffer

    const int tid  = threadIdx.x;
    const int b0   = blockIdx.x * NB;
    const int w    = tid >> 6;        // wave 0..15 = M-tile index (both layers)
    const int lane = tid & 63;
    const int n16  = lane & 15;       // A row (within tile) / B col / C col
    const int quad = lane >> 4;       // A k-group / C row-group

    // ---------------- persistent register state ----------------
    half8 aX;                         // L0 x-weights (k<5 real, rest 0)
    half8 a0[2];                      // L0 W_hh (on h1), K=64
    half8 a1h1[2];                    // L1 W_ih (on h1), K=64
    half8 a1h2[2];                    // L1 W_hh (on h2), K=64
    f32x4 bc0, bc1;                   // bias C-operands
    float c0 = 0.f, c1 = 0.f;         // cell states (u = w*4+quad, b = n16)

    const int u_c = w * 4 + quad;     // this lane's unit index, b = n16
    {
        const int u_a = w * 4 + (n16 >> 2);   // permuted u of this A row
        const int g_a = n16 & 3;              // gate of this A row (i,f,g,o)
        const int r0  = g_a * 64 + u_a;       // original weight row
        const float sc = (g_a == 2) ? 2.0f * LOG2E : LOG2E;   // exp2 pre-scale
        #pragma unroll
        for (int j = 0; j < 8; ++j) {
            const int k = quad * 8 + j;
            aX[j] = (k < D_IN) ? (_Float16)(sc * W_ih0[r0 * D_IN + k])
                               : (_Float16)0.f;
        }
        #pragma unroll
        for (int kt = 0; kt < 2; ++kt) {
            #pragma unroll
            for (int j = 0; j < 8; ++j) {
                const int kk = kt * 32 + quad * 8 + j;
                a0[kt][j]   = (_Float16)(sc * W_hh0[r0 * 64 + kk]);
                a1h1[kt][j] = (_Float16)(sc * W_ih1[r0 * 64 + kk]);
                a1h2[kt][j] = (_Float16)(sc * W_hh1[r0 * 64 + kk]);
            }
        }
        #pragma unroll
        for (int r = 0; r < 4; ++r) {
            const float scr = (r == 2) ? 2.0f * LOG2E : LOG2E;
            bc0[r] = scr * (b_ih0[r * 64 + u_c] + b_hh0[r * 64 + u_c]);
            bc1[r] = scr * (b_ih1[r * 64 + u_c] + b_hh1[r * 64 + u_c]);
        }
    }

    // ---------------- LDS init ----------------
    for (int i = tid; i < 2 * NB * 64; i += NTHREADS) (&h1b[0][0][0])[i] = (_Float16)0.f;
    for (int i = tid; i < 2 * NB * 64; i += NTHREADS) (&h2b[0][0][0])[i] = (_Float16)0.f;
    for (int i = tid; i < 2 * NB * 40; i += NTHREADS) (&x_pack[0][0][0])[i] = (_Float16)0.f;
    __syncthreads();

    // Balanced x-staging: wave w, lanes 0..4 stage batch row w (R12 put all
    // 80 staging lanes on waves 0-1 -> SIMDs 0-1 gated the barrier while
    // SIMDs 2-3 idled; now every SIMD carries the same staging cost).
    const bool xrole = (lane < D_IN);
    const float* xwrow = &x[((size_t)(b0 + w) * T_STEPS) * D_IN + lane];
    if (xrole) {   // x(0) -> buf 0, x(1) -> buf 1
        x_pack[0][w][lane] = (_Float16)xwrow[0];
        x_pack[1][w][lane] = (_Float16)xwrow[D_IN];
    }
    __syncthreads();

    // loop-invariant LDS offsets (in _Float16 units within a row)
    const int f0 = ((0 * 4 + quad) ^ (n16 & 7)) * 8;   // frag kt=0
    const int f1 = ((1 * 4 + quad) ^ (n16 & 7)) * 8;   // frag kt=1
    const int wo = hswz8(n16, u_c);                    // h write offset

    // cross-interval register pipeline:
    //   pacc0(t) = bc0 + Wx.x(t)           (computed at t-1; prologue for t=0)
    //   pacc1(t) = bc1 + W1h1.h1(t-2)      (computed at t-1; bc1 for t=0)
    f32x4 pacc0, pacc1;
    {
        const half8 bx0 = *reinterpret_cast<const half8*>(&x_pack[0][n16][quad * 8]);
        pacc0 = MFMA(aX, bx0, bc0);
        pacc1 = bc1;
    }

    #pragma unroll 2
    for (int t = 0; t <= T_STEPS + 1; ++t) {
        const int p = t & 1, q = p ^ 1;

        float xv = 0.f;   // prefetch x(t+2); staged at loop bottom
        if (xrole && (t + 2) < T_STEPS)
            xv = xwrow[(size_t)(t + 2) * D_IN];

        const _Float16* h1r = &h1b[q][n16][0];
        const _Float16* h2r = &h2b[q][n16][0];
        const half8 bx = *reinterpret_cast<const half8*>(&x_pack[q][n16][quad * 8]); // x(t+1)
        half8 bh1[2], bh2[2];                       // h1(t-1), h2(t-3)
        bh1[0] = *reinterpret_cast<const half8*>(h1r + f0);
        bh1[1] = *reinterpret_cast<const half8*>(h1r + f1);
        bh2[0] = *reinterpret_cast<const half8*>(h2r + f0);
        bh2[1] = *reinterpret_cast<const half8*>(h2r + f1);

        // ---- serial: L0 gates(t) and L1 gates(t-2) ----
        f32x4 acc0 = MFMA(a0[0],   bh1[0], pacc0);
        acc0       = MFMA(a0[1],   bh1[1], acc0);
        f32x4 acc1 = MFMA(a1h2[0], bh2[0], pacc1);
        acc1       = MFMA(a1h2[1], bh2[1], acc1);
        // ---- slack: next interval's partial accumulators ----
        pacc0 = MFMA(aX,      bx,     bc0);         // bc0 + Wx.x(t+1)
        pacc1 = MFMA(a1h1[0], bh1[0], bc1);         // bc1 + W1h1.h1(t-1)
        pacc1 = MFMA(a1h1[1], bh1[1], pacc1);

        // ---- L0 epilogue: h1(t) ----
        if (t < T_STEPS) {
            const float h = lstm_cell(acc0, c0);
            h1b[p][n16][wo] = (_Float16)h;
        }
        // ---- L1 epilogue: h2(t-2) ----
        if (t >= 2) {
            const float h = lstm_cell(acc1, c1);
            h2b[p][n16][wo] = (_Float16)h;
            if (t == T_STEPS + 1) h2f[n16][u_c] = h;   // exact h2(T-1)
        }
        if (xrole && (t + 2) < T_STEPS)     // stage x(t+2) into buf (t+2)&1 = p
            x_pack[p][w][lane] = (_Float16)xv;
        __syncthreads();
    }

    // ---------------- FC head: relu(h2_T @ W1^T + b1) @ W2^T + b2 ----------------
    if (tid < 512) {
        const int bb = tid >> 5;            // 0..15
        const int k  = tid & 31;            // 0..31
        float a = b1[k];
        #pragma unroll 16
        for (int j = 0; j < 64; ++j)
            a = fmaf(W1[k * 64 + j], h2f[bb][j], a);
        zb[bb][k] = fmaxf(a, 0.0f);
    }
    __syncthreads();
    if (tid < NB) {
        float a = b2[0];
        #pragma unroll
        for (int k = 0; k < 32; ++k) a = fmaf(W2[k], zb[tid][k], a);
        out[b0 + tid] = a;
    }
}

extern "C" void kernel_launch(void* const* d_in, const int* in_sizes, int n_in,
                              void* d_out, int out_size, void* d_ws, size_t ws_size,
                              hipStream_t stream) {
    (void)in_sizes; (void)n_in; (void)d_ws; (void)ws_size;
    const float* xp     = (const float*)d_in[0];
    const float* W_ih0  = (const float*)d_in[1];
    const float* W_hh0  = (const float*)d_in[2];
    const float* b_ih0  = (const float*)d_in[3];
    const float* b_hh0  = (const float*)d_in[4];
    const float* W_ih1  = (const float*)d_in[5];
    const float* W_hh1  = (const float*)d_in[6];
    const float* b_ih1  = (const float*)d_in[7];
    const float* b_hh1  = (const float*)d_in[8];
    const float* W1     = (const float*)d_in[9];
    const float* b1     = (const float*)d_in[10];
    const float* W2     = (const float*)d_in[11];
    const float* b2     = (const float*)d_in[12];
    float* outp = (float*)d_out;

    const int nblocks = out_size / NB;   // 4096/16 = 256, one block per CU
    hipLaunchKernelGGL(lstm_stack_mfma17, dim3(nblocks), dim3(NTHREADS), 0, stream,
                       xp, W_ih0, W_hh0, b_ih0, b_hh0,
                       W_ih1, W_hh1, b_ih1, b_hh1,
                       W1, b1, W2, b2, outp);
}

// Round 14
// 448.142 us; speedup vs baseline: 1.0988x; 1.0988x over previous
//
#include <hip/hip_runtime.h>
#include <cstddef>

#define T_STEPS  512
#define D_IN     5
#define NB       16      // batch elements per block
#define NTHREADS 1024    // 16 waves; each wave owns 1 L0 M-tile + 1 L1 M-tile
#define LOG2E    1.4426950408889634f

typedef _Float16 half8 __attribute__((ext_vector_type(8)));
typedef float    f32x4 __attribute__((ext_vector_type(4)));

// Builtin MFMA (R11/R12-proven): compiler manages accumulator hazards and
// interleaves epilogue VALU with MFMA issue (inline-asm pinned both; R12
// removing the s_nop fences was worth -60us).
#define MFMA(A, B, C) __builtin_amdgcn_mfma_f32_16x16x32_f16((A), (B), (C), 0, 0, 0)

// Weights pre-scaled by log2e (2*log2e for g rows) so activations use v_exp_f32.
// Single-rcp-per-product cell update: 7 trans ops (5 exp2 + 2 rcp) -- the
// floor for 3 sigmoids + 2 tanh with shared denominators (R8's cross-cell
// shared rcp overflowed fp32).
__device__ __forceinline__ float lstm_cell(const f32x4 acc, float& c) {
    const float tg = __builtin_amdgcn_exp2f(acc[2]);
    const float ui = __builtin_amdgcn_exp2f(-acc[0]);
    const float uf = __builtin_amdgcn_exp2f(-acc[1]);
    const float A  = 1.0f + uf;
    const float Bd = (1.0f + ui) * (1.0f + tg);
    const float r  = __builtin_amdgcn_rcpf(A * Bd);
    c = fmaf(c, Bd, (tg - 1.0f) * A) * r;
    const float ca = fminf(c * (2.0f * LOG2E), 126.0f);
    const float tc = __builtin_amdgcn_exp2f(ca);
    const float uo = __builtin_amdgcn_exp2f(-acc[3]);
    return (tc - 1.0f) * __builtin_amdgcn_rcpf((1.0f + uo) * (1.0f + tc));
}

// h-plane swizzle: row = 64 halves = 8 x 16B blocks; block j of row n lives at
// j ^ (n & 7). b128 reads conflict-free; scalar 2B writes 2-way (free).
__device__ __forceinline__ int hswz8(int n, int u) {
    return (((u >> 3) ^ (n & 7)) << 3) | (u & 7);
}

__global__ __launch_bounds__(NTHREADS, 4)
void lstm_stack_mfma18(const float* __restrict__ x,
                       const float* __restrict__ W_ih0,
                       const float* __restrict__ W_hh0,
                       const float* __restrict__ b_ih0,
                       const float* __restrict__ b_hh0,
                       const float* __restrict__ W_ih1,
                       const float* __restrict__ W_hh1,
                       const float* __restrict__ b_ih1,
                       const float* __restrict__ b_hh1,
                       const float* __restrict__ W1,
                       const float* __restrict__ b1,
                       const float* __restrict__ W2,
                       const float* __restrict__ b2,
                       float* __restrict__ out)
{
    // Lag-2 layer pipeline: interval t computes h1(t) (L0) and h2(t-2) (L1).
    // h planes double-buffered (write p=t&1, read q=p^1).
    // x double-buffered mod-2 (R13-proven): READ x(t+1) from buf (t+1)&1=q,
    // WRITE x(t+2) to buf (t+2)&1=p -- one barrier between producer and
    // consumer; all buffer indices constant-fold under unroll 2.
    // x staging stays CONCENTRATED on tid<80 (waves 0-1): R13 showed that
    // distributing it to all waves puts VMEM latency on every wave's path
    // to the barrier (-38us regression); specialization lets 14 compute-only
    // waves hide the 2 staging waves' latency.
    __shared__ _Float16 h1b[2][NB][64];         // h1, swizzled
    __shared__ _Float16 h2b[2][NB][64];         // h2, swizzled
    // x row = 40 halves (20 dw): bank = (20*n16+4*quad)%32, 2-way only.
    // Slots 0..4 written; 5..39 stay zero (zeros feed quads 1-3 of the frag).
    __shared__ _Float16 x_pack[2][NB][40];
    __shared__ float h2f[NB][68];   // exact fp32 h2(T-1) for FC head
    __shared__ float zb[NB][36];    // FC-head z buffer

    const int tid  = threadIdx.x;
    const int b0   = blockIdx.x * NB;
    const int w    = tid >> 6;        // wave 0..15 = M-tile index (both layers)
    const int lane = tid & 63;
    const int n16  = lane & 15;       // A row (within tile) / B col / C col
    const int quad = lane >> 4;       // A k-group / C row-group

    // ---------------- persistent register state ----------------
    half8 aX;                         // L0 x-weights (k<5 real, rest 0)
    half8 a0[2];                      // L0 W_hh (on h1), K=64
    half8 a1h1[2];                    // L1 W_ih (on h1), K=64
    half8 a1h2[2];                    // L1 W_hh (on h2), K=64
    f32x4 bc0, bc1;                   // bias C-operands
    float c0 = 0.f, c1 = 0.f;         // cell states (u = w*4+quad, b = n16)

    const int u_c = w * 4 + quad;     // this lane's unit index, b = n16
    {
        const int u_a = w * 4 + (n16 >> 2);   // permuted u of this A row
        const int g_a = n16 & 3;              // gate of this A row (i,f,g,o)
        const int r0  = g_a * 64 + u_a;       // original weight row
        const float sc = (g_a == 2) ? 2.0f * LOG2E : LOG2E;   // exp2 pre-scale
        #pragma unroll
        for (int j = 0; j < 8; ++j) {
            const int k = quad * 8 + j;
            aX[j] = (k < D_IN) ? (_Float16)(sc * W_ih0[r0 * D_IN + k])
                               : (_Float16)0.f;
        }
        #pragma unroll
        for (int kt = 0; kt < 2; ++kt) {
            #pragma unroll
            for (int j = 0; j < 8; ++j) {
                const int kk = kt * 32 + quad * 8 + j;
                a0[kt][j]   = (_Float16)(sc * W_hh0[r0 * 64 + kk]);
                a1h1[kt][j] = (_Float16)(sc * W_ih1[r0 * 64 + kk]);
                a1h2[kt][j] = (_Float16)(sc * W_hh1[r0 * 64 + kk]);
            }
        }
        #pragma unroll
        for (int r = 0; r < 4; ++r) {
            const float scr = (r == 2) ? 2.0f * LOG2E : LOG2E;
            bc0[r] = scr * (b_ih0[r * 64 + u_c] + b_hh0[r * 64 + u_c]);
            bc1[r] = scr * (b_ih1[r * 64 + u_c] + b_hh1[r * 64 + u_c]);
        }
    }

    // ---------------- LDS init ----------------
    for (int i = tid; i < 2 * NB * 64; i += NTHREADS) (&h1b[0][0][0])[i] = (_Float16)0.f;
    for (int i = tid; i < 2 * NB * 64; i += NTHREADS) (&h2b[0][0][0])[i] = (_Float16)0.f;
    for (int i = tid; i < 2 * NB * 40; i += NTHREADS) (&x_pack[0][0][0])[i] = (_Float16)0.f;
    __syncthreads();
    const int xb = tid / D_IN, xd = tid % D_IN;   // x-staging role (tid < 80)
    const bool xrole = (tid < NB * D_IN);
    if (xrole) {   // x(0) -> buf 0, x(1) -> buf 1
        const size_t base = (size_t)(b0 + xb) * T_STEPS;
        x_pack[0][xb][xd] = (_Float16)x[(base + 0) * D_IN + xd];
        x_pack[1][xb][xd] = (_Float16)x[(base + 1) * D_IN + xd];
    }
    __syncthreads();

    // loop-invariant LDS offsets (in _Float16 units within a row)
    const int f0 = ((0 * 4 + quad) ^ (n16 & 7)) * 8;   // frag kt=0
    const int f1 = ((1 * 4 + quad) ^ (n16 & 7)) * 8;   // frag kt=1
    const int wo = hswz8(n16, u_c);                    // h write offset

    // cross-interval register pipeline:
    //   pacc0(t) = bc0 + Wx.x(t)           (computed at t-1; prologue for t=0)
    //   pacc1(t) = bc1 + W1h1.h1(t-2)      (computed at t-1; bc1 for t=0)
    f32x4 pacc0, pacc1;
    {
        const half8 bx0 = *reinterpret_cast<const half8*>(&x_pack[0][n16][quad * 8]);
        pacc0 = MFMA(aX, bx0, bc0);
        pacc1 = bc1;
    }

    #pragma unroll 2
    for (int t = 0; t <= T_STEPS + 1; ++t) {
        const int p = t & 1, q = p ^ 1;

        float xv = 0.f;   // prefetch x(t+2); staged at loop bottom
        if (xrole && (t + 2) < T_STEPS)
            xv = x[((size_t)(b0 + xb) * T_STEPS + (t + 2)) * D_IN + xd];

        const _Float16* h1r = &h1b[q][n16][0];
        const _Float16* h2r = &h2b[q][n16][0];
        const half8 bx = *reinterpret_cast<const half8*>(&x_pack[q][n16][quad * 8]); // x(t+1)
        half8 bh1[2], bh2[2];                       // h1(t-1), h2(t-3)
        bh1[0] = *reinterpret_cast<const half8*>(h1r + f0);
        bh1[1] = *reinterpret_cast<const half8*>(h1r + f1);
        bh2[0] = *reinterpret_cast<const half8*>(h2r + f0);
        bh2[1] = *reinterpret_cast<const half8*>(h2r + f1);

        // ---- serial: L0 gates(t) and L1 gates(t-2) ----
        f32x4 acc0 = MFMA(a0[0],   bh1[0], pacc0);
        acc0       = MFMA(a0[1],   bh1[1], acc0);
        f32x4 acc1 = MFMA(a1h2[0], bh2[0], pacc1);
        acc1       = MFMA(a1h2[1], bh2[1], acc1);
        // ---- slack: next interval's partial accumulators ----
        pacc0 = MFMA(aX,      bx,     bc0);         // bc0 + Wx.x(t+1)
        pacc1 = MFMA(a1h1[0], bh1[0], bc1);         // bc1 + W1h1.h1(t-1)
        pacc1 = MFMA(a1h1[1], bh1[1], pacc1);

        // ---- L0 epilogue: h1(t) ----
        if (t < T_STEPS) {
            const float h = lstm_cell(acc0, c0);
            h1b[p][n16][wo] = (_Float16)h;
        }
        // ---- L1 epilogue: h2(t-2) ----
        if (t >= 2) {
            const float h = lstm_cell(acc1, c1);
            h2b[p][n16][wo] = (_Float16)h;
            if (t == T_STEPS + 1) h2f[n16][u_c] = h;   // exact h2(T-1)
        }
        if (xrole && (t + 2) < T_STEPS)     // stage x(t+2) into buf (t+2)&1 = p
            x_pack[p][xb][xd] = (_Float16)xv;
        __syncthreads();
    }

    // ---------------- FC head: relu(h2_T @ W1^T + b1) @ W2^T + b2 ----------------
    if (tid < 512) {
        const int bb = tid >> 5;            // 0..15
        const int k  = tid & 31;            // 0..31
        float a = b1[k];
        #pragma unroll 16
        for (int j = 0; j < 64; ++j)
            a = fmaf(W1[k * 64 + j], h2f[bb][j], a);
        zb[bb][k] = fmaxf(a, 0.0f);
    }
    __syncthreads();
    if (tid < NB) {
        float a = b2[0];
        #pragma unroll
        for (int k = 0; k < 32; ++k) a = fmaf(W2[k], zb[tid][k], a);
        out[b0 + tid] = a;
    }
}

extern "C" void kernel_launch(void* const* d_in, const int* in_sizes, int n_in,
                              void* d_out, int out_size, void* d_ws, size_t ws_size,
                              hipStream_t stream) {
    (void)in_sizes; (void)n_in; (void)d_ws; (void)ws_size;
    const float* xp     = (const float*)d_in[0];
    const float* W_ih0  = (const float*)d_in[1];
    const float* W_hh0  = (const float*)d_in[2];
    const float* b_ih0  = (const float*)d_in[3];
    const float* b_hh0  = (const float*)d_in[4];
    const float* W_ih1  = (const float*)d_in[5];
    const float* W_hh1  = (const float*)d_in[6];
    const float* b_ih1  = (const float*)d_in[7];
    const float* b_hh1  = (const float*)d_in[8];
    const float* W1     = (const float*)d_in[9];
    const float* b1     = (const float*)d_in[10];
    const float* W2     = (const float*)d_in[11];
    const float* b2     = (const float*)d_in[12];
    float* outp = (float*)d_out;

    const int nblocks = out_size / NB;   // 4096/16 = 256, one block per CU
    hipLaunchKernelGGL(lstm_stack_mfma18, dim3(nblocks), dim3(NTHREADS), 0, stream,
                       xp, W_ih0, W_hh0, b_ih0, b_hh0,
                       W_ih1, W_hh1, b_ih1, b_hh1,
                       W1, b1, W2, b2, outp);
}